// Round 14
// baseline (118.369 us; speedup 1.0000x reference)
//
#include <hip/hip_runtime.h>
#include <hip/hip_bf16.h>
#include <stdint.h>

// Problem constants
#define BB 16
#define SS 512
#define TT 16
#define DD 128
#define CH 64                 // s-rows per stage
#define NCH (SS/CH)           // 8
#define LN_EPS 1e-5f

typedef __attribute__((ext_vector_type(8))) short short8;
typedef __attribute__((ext_vector_type(4))) float f32x4;

#define SINK(x) asm volatile("" :: "v"(x))

// HW packed f32->bf16 (RNE): dst.lo = src0, dst.hi = src1
static __device__ __forceinline__ uint32_t cvt_pk_bf16(float lo, float hi) {
    uint32_t r;
    asm("v_cvt_pk_bf16_f32 %0, %1, %2" : "=v"(r) : "v"(lo), "v"(hi));
    return r;
}

// LDS-ordering barrier: does NOT drain vmcnt.
#define BAR() do {                                            \
    asm volatile("s_waitcnt lgkmcnt(0)" ::: "memory");        \
    __builtin_amdgcn_s_barrier();                             \
    asm volatile("" ::: "memory");                            \
} while (0)

// -----------------------------------------------------------------------------
// r12 structure, templated for ablation (rule #17: stripped values kept live
// via asm sinks so upstream work is not DCE'd):
//   MODE 0: full kernel, writes out + nexth        (the real dispatch)
//   MODE 1: no out/nexth stores (sink hE-products) -> isolates store cost
//   MODE 2: LN + GEMM+activation only (sink Cc/Cv) -> isolates scan cost
//   MODE 3: LN only (no ds_read/MFMA)              -> x-load+LN+barrier floor
// -----------------------------------------------------------------------------
template<int MODE>
__global__ __launch_bounds__(512, 2)
void fused_probe(
    const float* __restrict__ x, const float* __restrict__ prevh,
    const float* __restrict__ gamma, const float* __restrict__ beta,
    const float* __restrict__ W, const float* __restrict__ bias,
    float* __restrict__ out, float* __restrict__ nexth)
{
    __shared__ __align__(16) unsigned char xnb[2][CH*256];  // 2 x 16 KB bf16 xn

    const int tid  = threadIdx.x;
    const int w    = tid >> 6;           // 0..7
    const int lane = tid & 63;
    const int l15  = lane & 15;
    const int lhi  = lane >> 4;

    const int bt = blockIdx.x;
    const size_t rowstride = (size_t)TT * DD;               // 2048
    const size_t base_bt   = ((size_t)(bt >> 4) * SS * TT + (bt & 15)) * DD;

    // ---- LN lane assignment: 8 threads per row ----
    const int r_ln = tid >> 3;           // s-row 0..63 within chunk
    const int c8   = tid & 7;            // 16-float slot within the row
    const int slot_p = ((r_ln >> 2) & 3)*16 + (r_ln >> 4)*4 + (r_ln & 3);
    const int keyx   = slot_p & 7;
    const float* xp0 = x + base_bt + (size_t)r_ln * rowstride + c8*16;

    // ---- register prefetch of x chunk (16 VGPR) ----
    f32x4 px0, px1, px2, px3;
    auto issuePx = [&](int st) {
        const float* xp = xp0 + (size_t)st * CH * rowstride;
        px0 = *(const f32x4*)(xp + 0);
        px1 = *(const f32x4*)(xp + 4);
        px2 = *(const f32x4*)(xp + 8);
        px3 = *(const f32x4*)(xp + 12);
    };
    issuePx(0);

    // ---- build W fragments + folded bias in-kernel (all modes, equal) ----
    short8 wfr[2][4];
    float  bs2[2];
    #pragma unroll
    for (int ni = 0; ni < 2; ++ni) {
        const int col = (ni ? 128 : 0) + w*16 + l15;
        float acc = 0.0f;
        #pragma unroll
        for (int kt = 0; kt < 4; ++kt) {
            union { short8 s8; uint32_t u[4]; } fr;
            #pragma unroll
            for (int p = 0; p < 4; ++p) {
                const int k0 = kt*32 + lhi*8 + 2*p;
                const float w0 = W[(size_t)k0*256 + col];
                const float w1 = W[(size_t)(k0+1)*256 + col];
                acc = fmaf(beta[k0],   w0, acc);
                acc = fmaf(beta[k0+1], w1, acc);
                fr.u[p] = cvt_pk_bf16(gamma[k0]*w0, gamma[k0+1]*w1);
            }
            wfr[ni][kt] = fr.s8;
        }
        acc += __shfl_xor(acc, 16);
        acc += __shfl_xor(acc, 32);
        bs2[ni] = bias[col] + acc;
    }

    float hM = prevh[(size_t)bt*128 + w*16 + l15];

    // ---- LN: consume px regs -> xnb[st&1] at permuted slot (swizzled) ----
    auto phaseLN = [&](int st) {
        float s1 = px0.x+px0.y+px0.z+px0.w + px1.x+px1.y+px1.z+px1.w
                 + px2.x+px2.y+px2.z+px2.w + px3.x+px3.y+px3.z+px3.w;
        float s2 = px0.x*px0.x+px0.y*px0.y+px0.z*px0.z+px0.w*px0.w
                 + px1.x*px1.x+px1.y*px1.y+px1.z*px1.z+px1.w*px1.w
                 + px2.x*px2.x+px2.y*px2.y+px2.z*px2.z+px2.w*px2.w
                 + px3.x*px3.x+px3.y*px3.y+px3.z*px3.z+px3.w*px3.w;
        s1 += __shfl_xor(s1, 1); s2 += __shfl_xor(s2, 1);
        s1 += __shfl_xor(s1, 2); s2 += __shfl_xor(s2, 2);
        s1 += __shfl_xor(s1, 4); s2 += __shfl_xor(s2, 4);
        const float mu = s1 * (1.0f/128.0f);
        const float rs = rsqrtf(s2 * (1.0f/128.0f) - mu*mu + LN_EPS);
        unsigned char* row = xnb[st & 1] + slot_p*256;
        union { short8 s8; uint32_t u[4]; } a, b2;
        a.u[0]  = cvt_pk_bf16((px0.x-mu)*rs, (px0.y-mu)*rs);
        a.u[1]  = cvt_pk_bf16((px0.z-mu)*rs, (px0.w-mu)*rs);
        a.u[2]  = cvt_pk_bf16((px1.x-mu)*rs, (px1.y-mu)*rs);
        a.u[3]  = cvt_pk_bf16((px1.z-mu)*rs, (px1.w-mu)*rs);
        b2.u[0] = cvt_pk_bf16((px2.x-mu)*rs, (px2.y-mu)*rs);
        b2.u[1] = cvt_pk_bf16((px2.z-mu)*rs, (px2.w-mu)*rs);
        b2.u[2] = cvt_pk_bf16((px3.x-mu)*rs, (px3.y-mu)*rs);
        b2.u[3] = cvt_pk_bf16((px3.z-mu)*rs, (px3.w-mu)*rs);
        *(short8*)(row + (((2*c8)     ^ keyx) << 4)) = a.s8;
        *(short8*)(row + (((2*c8 + 1) ^ keyx) << 4)) = b2.s8;
    };

    // ---- GEMM + activation + scan + stores (per MODE) ----
    auto phaseG = [&](int st) {
        if constexpr (MODE >= 3) return;
        const unsigned char* xb = xnb[st & 1];
        float Cc[16], Cv[16];
        #pragma unroll
        for (int mt = 0; mt < 4; ++mt) {
            const unsigned char* rowp = xb + (mt*16 + l15)*256;
            short8 af[4];
            #pragma unroll
            for (int kt = 0; kt < 4; ++kt) {
                const int c = (kt << 2) | lhi;
                af[kt] = *(const short8*)(rowp + ((c ^ (l15 & 7)) << 4));
            }
            f32x4 ag = (f32x4)(0.f), ah = (f32x4)(0.f);
            #pragma unroll
            for (int kt = 0; kt < 4; ++kt) {
                ag = __builtin_amdgcn_mfma_f32_16x16x32_bf16(af[kt], wfr[0][kt], ag, 0, 0, 0);
                ah = __builtin_amdgcn_mfma_f32_16x16x32_bf16(af[kt], wfr[1][kt], ah, 0, 0, 0);
            }
            #pragma unroll
            for (int j = 0; j < 4; ++j) {
                const float g  = ag[j] + bs2[0];
                const float hh = ah[j] + bs2[1];
                const float cc = 1.0f / (1.0f + __expf(g));
                const float ga = (hh >= 0.0f) ? (hh + 0.5f)
                                              : (1.0f / (1.0f + __expf(-hh)));
                Cc[mt*4 + j] = cc;
                Cv[mt*4 + j] = (1.0f - cc) * ga;
            }
        }
        if constexpr (MODE == 2) {           // stop after activation
            #pragma unroll
            for (int i = 0; i < 16; ++i) { SINK(Cc[i]); SINK(Cv[i]); }
            return;
        }
        #pragma unroll
        for (int i = 1; i < 16; ++i) {       // lane-local prefix, 16 rows
            Cv[i] = fmaf(Cc[i], Cv[i-1], Cv[i]);
            Cc[i] = Cc[i] * Cc[i-1];
        }
        float Ic = Cc[15], Iv = Cv[15];      // cross-lhi Hillis-Steele
        float pc = __shfl_up(Ic, 16), pv = __shfl_up(Iv, 16);
        if (lhi >= 1) { Iv = fmaf(Ic, pv, Iv); Ic *= pc; }
        pc = __shfl_up(Ic, 32); pv = __shfl_up(Iv, 32);
        if (lhi >= 2) { Iv = fmaf(Ic, pv, Iv); Ic *= pc; }
        float Ec = __shfl_up(Ic, 16), Ev = __shfl_up(Iv, 16);
        if (lhi == 0) { Ec = 1.0f; Ev = 0.0f; }
        const float Mc = __shfl(Ic, 48 + l15);
        const float Mv = __shfl(Iv, 48 + l15);
        const float hE = fmaf(Ec, hM, Ev);
        float* op = out + base_bt + (size_t)(st*CH + lhi*16) * rowstride + w*16 + l15;
        #pragma unroll
        for (int i = 0; i < 16; ++i) {
            const float v = fmaf(Cc[i], hE, Cv[i]);
            if constexpr (MODE == 0) op[(size_t)i * rowstride] = v;
            else                     SINK(v);
        }
        hM = fmaf(Mc, hM, Mv);
    };

    // ---- prologue ----
    phaseLN(0);
    issuePx(1);
    BAR();

    // ---- main: one barrier per stage ----
    for (int st = 0; st < NCH; ++st) {
        phaseG(st);
        if (st + 1 < NCH) {
            phaseLN(st + 1);
            if (st + 2 < NCH) issuePx(st + 2);
        }
        BAR();
    }

    if constexpr (MODE == 0) {
        if (lane < 16)
            nexth[(size_t)bt*128 + w*16 + lane] = hM;
    } else if constexpr (MODE <= 2) {
        SINK(hM);
    } else {
        // MODE 3: keep the LN LDS writes observable
        float t0 = *(float*)&xnb[0][(tid*4) & (CH*256 - 4)];
        SINK(t0);
        SINK(hM);
    }
}

extern "C" void kernel_launch(void* const* d_in, const int* in_sizes, int n_in,
                              void* d_out, int out_size, void* d_ws, size_t ws_size,
                              hipStream_t stream) {
    const float* x     = (const float*)d_in[0];
    const float* prevh = (const float*)d_in[1];
    const float* gamma = (const float*)d_in[2];
    const float* beta  = (const float*)d_in[3];
    const float* W     = (const float*)d_in[4];
    const float* bias  = (const float*)d_in[5];

    float* out   = (float*)d_out;
    float* nexth = out + (size_t)BB*SS*TT*DD;              // 16777216

    // real kernel (MODE 0) first; then non-writing ablation probes
    fused_probe<0><<<BB*TT, 512, 0, stream>>>(x, prevh, gamma, beta, W, bias, out, nexth);
    fused_probe<1><<<BB*TT, 512, 0, stream>>>(x, prevh, gamma, beta, W, bias, out, nexth);
    fused_probe<2><<<BB*TT, 512, 0, stream>>>(x, prevh, gamma, beta, W, bias, out, nexth);
    fused_probe<3><<<BB*TT, 512, 0, stream>>>(x, prevh, gamma, beta, W, bias, out, nexth);
}

// Round 16
// 51.542 us; speedup vs baseline: 2.2965x; 2.2965x over previous
//
#include <hip/hip_runtime.h>
#include <hip/hip_bf16.h>
#include <stdint.h>

// Problem constants
#define BB 16
#define SS 512
#define TT 16
#define DD 128
#define CH 64                 // s-rows per stage
#define NCH (SS/CH)           // 8
#define LN_EPS 1e-5f

typedef __attribute__((ext_vector_type(8))) short short8;
typedef __attribute__((ext_vector_type(4))) float f32x4;

// HW packed f32->bf16 (RNE): dst.lo = src0, dst.hi = src1
static __device__ __forceinline__ uint32_t cvt_pk_bf16(float lo, float hi) {
    uint32_t r;
    asm("v_cvt_pk_bf16_f32 %0, %1, %2" : "=v"(r) : "v"(lo), "v"(hi));
    return r;
}

// LDS-ordering barrier: does NOT drain vmcnt.
#define BAR() do {                                            \
    asm volatile("s_waitcnt lgkmcnt(0)" ::: "memory");        \
    __builtin_amdgcn_s_barrier();                             \
    asm volatile("" ::: "memory");                            \
} while (0)

// -----------------------------------------------------------------------------
// 2 blocks per (b,t) chain — one per 64-column half — so each CU carries TWO
// independent blocks whose barriers/stalls overlap. 256 threads = 4 waves.
// Wave w owns cols half*64 + [w*16, w*16+16) (gate) and +128 (hidden).
// Per 64-row stage (one barrier each):
//   phaseG(st): 4 m-tiles MFMA+activation -> Cc/Cv regs; lane-local 16-row
//               prefix; cross-lhi Hillis-Steele (5 shuffles); 16 stores; hM.
//   phaseLN(st+1): 4 threads/row from register-prefetched x (32 f32/thread),
//               row permutation s = lhi*16 + mt*4 + j -> A-slot mt*16+lhi*4+j,
//               bank-swizzled bf16 LDS write.
//   issuePx(st+2): register prefetch of next-next x chunk.
// LN + x loads are duplicated across the column-half pair (L2/L3-absorbed);
// GEMM/scan/stores are not duplicated.
// -----------------------------------------------------------------------------
__global__ __launch_bounds__(256, 2) void fused_mingru(
    const float* __restrict__ x, const float* __restrict__ prevh,
    const float* __restrict__ gamma, const float* __restrict__ beta,
    const float* __restrict__ W, const float* __restrict__ bias,
    float* __restrict__ out, float* __restrict__ nexth)
{
    __shared__ __align__(16) unsigned char xnb[2][CH*256];  // 2 x 16 KB bf16 xn

    const int tid  = threadIdx.x;
    const int w    = tid >> 6;           // 0..3
    const int lane = tid & 63;
    const int l15  = lane & 15;
    const int lhi  = lane >> 4;

    const int bt   = blockIdx.x >> 1;
    const int half = blockIdx.x & 1;     // which 64-col half this block owns
    const size_t rowstride = (size_t)TT * DD;               // 2048
    const size_t base_bt   = ((size_t)(bt >> 4) * SS * TT + (bt & 15)) * DD;

    // ---- LN lane assignment: 4 threads per row, 32 floats each ----
    const int r_ln = tid >> 2;           // s-row 0..63 within chunk
    const int c4   = tid & 3;            // quarter of the row
    const int slot_p = ((r_ln >> 2) & 3)*16 + (r_ln >> 4)*4 + (r_ln & 3);
    const int keyx   = slot_p & 7;
    const float* xp0 = x + base_bt + (size_t)r_ln * rowstride + c4*32;

    // ---- register prefetch of x chunk (32 VGPR) ----
    f32x4 px[8];
    auto issuePx = [&](int st) {
        const float* xp = xp0 + (size_t)st * CH * rowstride;
        #pragma unroll
        for (int q = 0; q < 8; ++q)
            px[q] = *(const f32x4*)(xp + q*4);
    };
    issuePx(0);   // latency hidden under the W-fragment build

    // ---- build W fragments + folded bias in-kernel ----
    short8 wfr[2][4];
    float  bs2[2];
    #pragma unroll
    for (int ni = 0; ni < 2; ++ni) {
        const int col = (ni ? 128 : 0) + half*64 + w*16 + l15;
        float acc = 0.0f;
        #pragma unroll
        for (int kt = 0; kt < 4; ++kt) {
            union { short8 s8; uint32_t u[4]; } fr;
            #pragma unroll
            for (int p = 0; p < 4; ++p) {
                const int k0 = kt*32 + lhi*8 + 2*p;
                const float w0 = W[(size_t)k0*256 + col];
                const float w1 = W[(size_t)(k0+1)*256 + col];
                acc = fmaf(beta[k0],   w0, acc);
                acc = fmaf(beta[k0+1], w1, acc);
                fr.u[p] = cvt_pk_bf16(gamma[k0]*w0, gamma[k0+1]*w1);
            }
            wfr[ni][kt] = fr.s8;
        }
        acc += __shfl_xor(acc, 16);
        acc += __shfl_xor(acc, 32);
        bs2[ni] = bias[col] + acc;
    }

    // running h for this wave's 16 columns (replicated across lhi groups)
    float hM = prevh[(size_t)bt*128 + half*64 + w*16 + l15];

    // ---- LN: consume px regs -> xnb[st&1] at permuted slot (swizzled) ----
    auto phaseLN = [&](int st) {
        float s1 = 0.f, s2 = 0.f;
        #pragma unroll
        for (int q = 0; q < 8; ++q) {
            s1 += px[q].x + px[q].y + px[q].z + px[q].w;
            s2 += px[q].x*px[q].x + px[q].y*px[q].y
                + px[q].z*px[q].z + px[q].w*px[q].w;
        }
        s1 += __shfl_xor(s1, 1); s2 += __shfl_xor(s2, 1);
        s1 += __shfl_xor(s1, 2); s2 += __shfl_xor(s2, 2);
        const float mu = s1 * (1.0f/128.0f);
        const float rs = rsqrtf(s2 * (1.0f/128.0f) - mu*mu + LN_EPS);
        unsigned char* row = xnb[st & 1] + slot_p*256;
        #pragma unroll
        for (int m = 0; m < 4; ++m) {
            union { short8 s8; uint32_t u[4]; } a;
            a.u[0] = cvt_pk_bf16((px[2*m].x  -mu)*rs, (px[2*m].y  -mu)*rs);
            a.u[1] = cvt_pk_bf16((px[2*m].z  -mu)*rs, (px[2*m].w  -mu)*rs);
            a.u[2] = cvt_pk_bf16((px[2*m+1].x-mu)*rs, (px[2*m+1].y-mu)*rs);
            a.u[3] = cvt_pk_bf16((px[2*m+1].z-mu)*rs, (px[2*m+1].w-mu)*rs);
            const int ci = c4*4 + m;                         // 16B chunk 0..15
            *(short8*)(row + ((ci ^ keyx) << 4)) = a.s8;
        }
    };

    // ---- GEMM + activation + stage-wide in-register scan + out stores ----
    auto phaseG = [&](int st) {
        const unsigned char* xb = xnb[st & 1];
        float Cc[16], Cv[16];            // s = lhi*16 + idx, idx = mt*4 + j
        #pragma unroll
        for (int mt = 0; mt < 4; ++mt) {
            const unsigned char* rowp = xb + (mt*16 + l15)*256;
            short8 af[4];
            #pragma unroll
            for (int kt = 0; kt < 4; ++kt) {
                const int c = (kt << 2) | lhi;
                af[kt] = *(const short8*)(rowp + ((c ^ (l15 & 7)) << 4));
            }
            f32x4 ag = (f32x4)(0.f), ah = (f32x4)(0.f);
            #pragma unroll
            for (int kt = 0; kt < 4; ++kt) {
                ag = __builtin_amdgcn_mfma_f32_16x16x32_bf16(af[kt], wfr[0][kt], ag, 0, 0, 0);
                ah = __builtin_amdgcn_mfma_f32_16x16x32_bf16(af[kt], wfr[1][kt], ah, 0, 0, 0);
            }
            #pragma unroll
            for (int j = 0; j < 4; ++j) {
                const float g  = ag[j] + bs2[0];
                const float hh = ah[j] + bs2[1];
                const float cc = 1.0f / (1.0f + __expf(g));
                const float ga = (hh >= 0.0f) ? (hh + 0.5f)
                                              : (1.0f / (1.0f + __expf(-hh)));
                Cc[mt*4 + j] = cc;
                Cv[mt*4 + j] = (1.0f - cc) * ga;
            }
        }
        #pragma unroll
        for (int i = 1; i < 16; ++i) {          // lane-local prefix, 16 rows
            Cv[i] = fmaf(Cc[i], Cv[i-1], Cv[i]);
            Cc[i] = Cc[i] * Cc[i-1];
        }
        float Ic = Cc[15], Iv = Cv[15];         // cross-lhi Hillis-Steele
        float pc = __shfl_up(Ic, 16), pv = __shfl_up(Iv, 16);
        if (lhi >= 1) { Iv = fmaf(Ic, pv, Iv); Ic *= pc; }
        pc = __shfl_up(Ic, 32); pv = __shfl_up(Iv, 32);
        if (lhi >= 2) { Iv = fmaf(Ic, pv, Iv); Ic *= pc; }
        float Ec = __shfl_up(Ic, 16), Ev = __shfl_up(Iv, 16);
        if (lhi == 0) { Ec = 1.0f; Ev = 0.0f; }
        const float Mc = __shfl(Ic, 48 + l15);
        const float Mv = __shfl(Iv, 48 + l15);
        const float hE = fmaf(Ec, hM, Ev);      // h before row lhi*16
        float* op = out + base_bt + (size_t)(st*CH + lhi*16) * rowstride
                  + half*64 + w*16 + l15;
        #pragma unroll
        for (int i = 0; i < 16; ++i)
            op[(size_t)i * rowstride] = fmaf(Cc[i], hE, Cv[i]);
        hM = fmaf(Mc, hM, Mv);
    };

    // ---- prologue: LN(0) (waits px0), prefetch x(1) ----
    phaseLN(0);
    issuePx(1);
    BAR();

    // ---- main: one barrier per stage ----
    for (int st = 0; st < NCH; ++st) {
        phaseG(st);
        if (st + 1 < NCH) {
            phaseLN(st + 1);                 // consumes px(st+1)
            if (st + 2 < NCH) issuePx(st + 2);
        }
        BAR();
    }

    if (lane < 16)
        nexth[(size_t)bt*128 + half*64 + w*16 + lane] = hM;
}

extern "C" void kernel_launch(void* const* d_in, const int* in_sizes, int n_in,
                              void* d_out, int out_size, void* d_ws, size_t ws_size,
                              hipStream_t stream) {
    const float* x     = (const float*)d_in[0];
    const float* prevh = (const float*)d_in[1];
    const float* gamma = (const float*)d_in[2];
    const float* beta  = (const float*)d_in[3];
    const float* W     = (const float*)d_in[4];
    const float* bias  = (const float*)d_in[5];

    float* out   = (float*)d_out;
    float* nexth = out + (size_t)BB*SS*TT*DD;              // 16777216

    fused_mingru<<<BB*TT*2, 256, 0, stream>>>(x, prevh, gamma, beta, W, bias,
                                              out, nexth);
}

// Round 18
// 47.457 us; speedup vs baseline: 2.4943x; 1.0861x over previous
//
#include <hip/hip_runtime.h>
#include <hip/hip_bf16.h>
#include <stdint.h>

// Problem constants
#define BB 16
#define SS 512
#define TT 16
#define DD 128
#define CH 64                 // s-rows per stage
#define NCH (SS/CH)           // 8
#define LN_EPS 1e-5f

typedef __attribute__((ext_vector_type(8))) short short8;
typedef __attribute__((ext_vector_type(4))) float f32x4;

// HW packed f32->bf16 (RNE): dst.lo = src0, dst.hi = src1
static __device__ __forceinline__ uint32_t cvt_pk_bf16(float lo, float hi) {
    uint32_t r;
    asm("v_cvt_pk_bf16_f32 %0, %1, %2" : "=v"(r) : "v"(lo), "v"(hi));
    return r;
}

// LDS-ordering barrier: does NOT drain vmcnt.
#define BAR() do {                                            \
    asm volatile("s_waitcnt lgkmcnt(0)" ::: "memory");        \
    __builtin_amdgcn_s_barrier();                             \
    asm volatile("" ::: "memory");                            \
} while (0)

// -----------------------------------------------------------------------------
// One block per (b,t) chain, 1024 threads = 16 waves = 4 waves/SIMD.
// Wave (q = wave>>3, w = wave&7): q = row-half of each stage, w = 16-col group
// (gate cols w*16.., hidden cols 128+w*16.. — pairing preserved per wave).
// Row permutation: s = q*32 + lhi*8 + mt*4 + j  <->  A-slot (2q+mt)*16+lhi*4+j,
// so each lane owns 8 CONSECUTIVE s-rows of its half.
// Per stage: part1 = {2 m-tiles MFMA + activation -> Cc/Cv[8]; 8-row lane
// prefix; 2-round cross-lhi Hillis-Steele; write half-composite M_q to LDS}
// ∥ phaseLN(st+1); BAR; part2 = {read M_0,M_1; hE; 8 stores; hM = M1∘M0∘hM;
// issuePx(st+2)}; BAR.
// -----------------------------------------------------------------------------
__global__ __launch_bounds__(1024, 4) void fused_mingru(
    const float* __restrict__ x, const float* __restrict__ prevh,
    const float* __restrict__ gamma, const float* __restrict__ beta,
    const float* __restrict__ W, const float* __restrict__ bias,
    float* __restrict__ out, float* __restrict__ nexth)
{
    __shared__ __align__(16) unsigned char xnb[2][CH*256];  // 2 x 16 KB bf16 xn
    __shared__ float2 Mex[2][8][16];                        // 2 KB half-composites

    const int tid  = threadIdx.x;
    const int wave = tid >> 6;           // 0..15
    const int q    = wave >> 3;          // row-half 0/1
    const int w    = wave & 7;           // col group 0..7
    const int lane = tid & 63;
    const int l15  = lane & 15;
    const int lhi  = lane >> 4;

    const int bt = blockIdx.x;
    const size_t rowstride = (size_t)TT * DD;               // 2048
    const size_t base_bt   = ((size_t)(bt >> 4) * SS * TT + (bt & 15)) * DD;

    // ---- LN lane assignment: 16 threads per row, 8 floats each ----
    const int r_ln = tid >> 4;           // s-row 0..63 within chunk
    const int c16  = tid & 15;           // 8-float (16 B) slot within the row
    const int remq = r_ln & 31;
    const int slot_p = ((r_ln >> 5)*2 + ((remq >> 2) & 1))*16
                     + (remq >> 3)*4 + (remq & 3);
    const int keyx   = slot_p & 7;
    const float* xp0 = x + base_bt + (size_t)r_ln * rowstride + c16*8;

    // ---- register prefetch of x (8 VGPR) ----
    f32x4 pxa, pxb;
    auto issuePx = [&](int st) {
        const float* xp = xp0 + (size_t)st * CH * rowstride;
        pxa = *(const f32x4*)(xp + 0);
        pxb = *(const f32x4*)(xp + 4);
    };
    issuePx(0);   // latency hidden under the W-fragment build

    // ---- build W fragments + folded bias (q=0/1 duplicate; prologue-only) ----
    short8 wfr[2][4];
    float  bs2[2];
    #pragma unroll
    for (int ni = 0; ni < 2; ++ni) {
        const int col = (ni ? 128 : 0) + w*16 + l15;
        float acc = 0.0f;
        #pragma unroll
        for (int kt = 0; kt < 4; ++kt) {
            union { short8 s8; uint32_t u[4]; } fr;
            #pragma unroll
            for (int p = 0; p < 4; ++p) {
                const int k0 = kt*32 + lhi*8 + 2*p;
                const float w0 = W[(size_t)k0*256 + col];
                const float w1 = W[(size_t)(k0+1)*256 + col];
                acc = fmaf(beta[k0],   w0, acc);
                acc = fmaf(beta[k0+1], w1, acc);
                fr.u[p] = cvt_pk_bf16(gamma[k0]*w0, gamma[k0+1]*w1);
            }
            wfr[ni][kt] = fr.s8;
        }
        acc += __shfl_xor(acc, 16);
        acc += __shfl_xor(acc, 32);
        bs2[ni] = bias[col] + acc;
    }

    // running h for this wave's 16 columns (replicated across lhi and q)
    float hM = prevh[(size_t)bt*128 + w*16 + l15];

    // ---- LN: consume px regs -> xnb[st&1] at permuted slot (swizzled) ----
    auto phaseLN = [&](int st) {
        float s1 = pxa.x+pxa.y+pxa.z+pxa.w + pxb.x+pxb.y+pxb.z+pxb.w;
        float s2 = pxa.x*pxa.x+pxa.y*pxa.y+pxa.z*pxa.z+pxa.w*pxa.w
                 + pxb.x*pxb.x+pxb.y*pxb.y+pxb.z*pxb.z+pxb.w*pxb.w;
        s1 += __shfl_xor(s1, 1); s2 += __shfl_xor(s2, 1);
        s1 += __shfl_xor(s1, 2); s2 += __shfl_xor(s2, 2);
        s1 += __shfl_xor(s1, 4); s2 += __shfl_xor(s2, 4);
        s1 += __shfl_xor(s1, 8); s2 += __shfl_xor(s2, 8);
        const float mu = s1 * (1.0f/128.0f);
        const float rs = rsqrtf(s2 * (1.0f/128.0f) - mu*mu + LN_EPS);
        union { short8 s8; uint32_t u[4]; } a;
        a.u[0] = cvt_pk_bf16((pxa.x-mu)*rs, (pxa.y-mu)*rs);
        a.u[1] = cvt_pk_bf16((pxa.z-mu)*rs, (pxa.w-mu)*rs);
        a.u[2] = cvt_pk_bf16((pxb.x-mu)*rs, (pxb.y-mu)*rs);
        a.u[3] = cvt_pk_bf16((pxb.z-mu)*rs, (pxb.w-mu)*rs);
        *(short8*)(xnb[st & 1] + slot_p*256 + ((c16 ^ keyx) << 4)) = a.s8;
    };

    // ---- per-stage state carried part1 -> part2 ----
    float Cc[8], Cv[8], Ec, Ev;

    // part1: MFMA + activation + lane prefix + cross-lhi HS + publish M_q
    auto part1 = [&](int st) {
        const unsigned char* xb = xnb[st & 1];
        #pragma unroll
        for (int mt = 0; mt < 2; ++mt) {
            const unsigned char* rowp = xb + (((2*q + mt)*16 + l15))*256;
            short8 af[4];
            #pragma unroll
            for (int kt = 0; kt < 4; ++kt) {
                const int c = (kt << 2) | lhi;
                af[kt] = *(const short8*)(rowp + ((c ^ (l15 & 7)) << 4));
            }
            f32x4 ag = (f32x4)(0.f), ah = (f32x4)(0.f);
            #pragma unroll
            for (int kt = 0; kt < 4; ++kt) {
                ag = __builtin_amdgcn_mfma_f32_16x16x32_bf16(af[kt], wfr[0][kt], ag, 0, 0, 0);
                ah = __builtin_amdgcn_mfma_f32_16x16x32_bf16(af[kt], wfr[1][kt], ah, 0, 0, 0);
            }
            #pragma unroll
            for (int j = 0; j < 4; ++j) {
                const float g  = ag[j] + bs2[0];
                const float hh = ah[j] + bs2[1];
                const float cc = 1.0f / (1.0f + __expf(g));
                const float ga = (hh >= 0.0f) ? (hh + 0.5f)
                                              : (1.0f / (1.0f + __expf(-hh)));
                Cc[mt*4 + j] = cc;
                Cv[mt*4 + j] = (1.0f - cc) * ga;
            }
        }
        #pragma unroll
        for (int i = 1; i < 8; ++i) {        // lane-local prefix, 8 rows
            Cv[i] = fmaf(Cc[i], Cv[i-1], Cv[i]);
            Cc[i] = Cc[i] * Cc[i-1];
        }
        float Ic = Cc[7], Iv = Cv[7];        // cross-lhi Hillis-Steele (half)
        float pc = __shfl_up(Ic, 16), pv = __shfl_up(Iv, 16);
        if (lhi >= 1) { Iv = fmaf(Ic, pv, Iv); Ic *= pc; }
        pc = __shfl_up(Ic, 32); pv = __shfl_up(Iv, 32);
        if (lhi >= 2) { Iv = fmaf(Ic, pv, Iv); Ic *= pc; }
        Ec = __shfl_up(Ic, 16); Ev = __shfl_up(Iv, 16);
        if (lhi == 0) { Ec = 1.0f; Ev = 0.0f; }
        const float Mc = __shfl(Ic, 48 + l15);   // half-composite (32 rows)
        const float Mv = __shfl(Iv, 48 + l15);
        if (lane < 16) Mex[q][w][lane] = make_float2(Mc, Mv);
    };

    // part2: combine halves, store outputs, advance hM
    auto part2 = [&](int st) {
        const float2 m0 = Mex[0][w][l15];
        const float2 m1 = Mex[1][w][l15];
        const float h0 = fmaf(m0.x, hM, m0.y);   // h after half 0
        const float X  = q ? h0 : hM;            // h at this half's start
        const float hE = fmaf(Ec, X, Ev);        // h before row lhi*8
        float* op = out + base_bt
                  + (size_t)(st*CH + q*32 + lhi*8) * rowstride + w*16 + l15;
        #pragma unroll
        for (int i = 0; i < 8; ++i)
            op[(size_t)i * rowstride] = fmaf(Cc[i], hE, Cv[i]);
        hM = fmaf(m1.x, h0, m1.y);               // full-stage composite
    };

    // ---- prologue: LN(0) (waits px0), prefetch x(1) ----
    phaseLN(0);
    issuePx(1);
    BAR();

    // ---- main: two barriers per stage ----
    for (int st = 0; st < NCH; ++st) {
        part1(st);
        if (st + 1 < NCH) phaseLN(st + 1);       // consumes px(st+1)
        BAR();                                   // M_q published; xn(st+1) done
        part2(st);
        if (st + 2 < NCH) issuePx(st + 2);
        BAR();                                   // Mex reads done before reuse
    }

    if (q == 0 && lane < 16)
        nexth[(size_t)bt*128 + w*16 + lane] = hM;
}

extern "C" void kernel_launch(void* const* d_in, const int* in_sizes, int n_in,
                              void* d_out, int out_size, void* d_ws, size_t ws_size,
                              hipStream_t stream) {
    const float* x     = (const float*)d_in[0];
    const float* prevh = (const float*)d_in[1];
    const float* gamma = (const float*)d_in[2];
    const float* beta  = (const float*)d_in[3];
    const float* W     = (const float*)d_in[4];
    const float* bias  = (const float*)d_in[5];

    float* out   = (float*)d_out;
    float* nexth = out + (size_t)BB*SS*TT*DD;              // 16777216

    fused_mingru<<<BB*TT, 1024, 0, stream>>>(x, prevh, gamma, beta, W, bias,
                                             out, nexth);
}

// Round 22
// 42.354 us; speedup vs baseline: 2.7947x; 1.1205x over previous
//
#include <hip/hip_runtime.h>
#include <hip/hip_bf16.h>
#include <stdint.h>

// Problem constants
#define BB 16
#define SS 512
#define TT 16
#define DD 128
#define CH 64                 // s-rows per stage
#define NCH (SS/CH)           // 8
#define LN_EPS 1e-5f

typedef __attribute__((ext_vector_type(8))) short short8;
typedef __attribute__((ext_vector_type(4))) float f32x4;

// HW packed f32->bf16 (RNE): dst.lo = src0, dst.hi = src1
static __device__ __forceinline__ uint32_t cvt_pk_bf16(float lo, float hi) {
    uint32_t r;
    asm("v_cvt_pk_bf16_f32 %0, %1, %2" : "=v"(r) : "v"(lo), "v"(hi));
    return r;
}

// LDS-ordering barrier: does NOT drain vmcnt.
#define BAR() do {                                            \
    asm volatile("s_waitcnt lgkmcnt(0)" ::: "memory");        \
    __builtin_amdgcn_s_barrier();                             \
    asm volatile("" ::: "memory");                            \
} while (0)

// -----------------------------------------------------------------------------
// r12 structure (best measured: 41.9 us), ONE experimental change: declare the
// true residency via __launch_bounds__(512, 2) — 2nd arg = min waves/EU — so
// the register allocator stops minimizing VGPRs for occupancy that a 1-block/CU
// persistent kernel can never use. r12 compiled to 64 VGPR, which forces the
// px x-prefetch to be re-sunk into phaseLN (exposed L2/L3 latency per stage).
// With the cap lifted (256 VGPR @ 2 waves/EU), px(16)+wfr(16)+Cc/Cv(32) stay
// resident and the one-stage-ahead prefetch becomes real.
//
// One block per (b,t) chain, 512 threads = 8 waves (2/SIMD).
// Wave w owns output cols [w*16,w*16+16) (gate) and +128 (hidden).
// Row permutation: LN writes s-row s to A-slot (mt*16+lhi*4+j) where
// s = lhi*16 + mt*4 + j -> each lane owns 16 CONSECUTIVE s-rows.
// Per stage (one barrier each):
//   phaseG(st): 4 m-tiles MFMA+activation -> Cc/Cv; lane-local 16-row prefix;
//               cross-lhi Hillis-Steele (5 shuffles); 16 stores; hM advance.
//   phaseLN(st+1): from register-prefetched x; bf16 via cvt_pk; swizzled write.
//   issuePx(st+2): register prefetch of next-next x chunk.
// -----------------------------------------------------------------------------
__global__ __launch_bounds__(512, 2)
void fused_mingru(
    const float* __restrict__ x, const float* __restrict__ prevh,
    const float* __restrict__ gamma, const float* __restrict__ beta,
    const float* __restrict__ W, const float* __restrict__ bias,
    float* __restrict__ out, float* __restrict__ nexth)
{
    __shared__ __align__(16) unsigned char xnb[2][CH*256];  // 2 x 16 KB bf16 xn

    const int tid  = threadIdx.x;
    const int w    = tid >> 6;           // 0..7
    const int lane = tid & 63;
    const int l15  = lane & 15;
    const int lhi  = lane >> 4;

    const int bt = blockIdx.x;
    const size_t rowstride = (size_t)TT * DD;               // 2048
    const size_t base_bt   = ((size_t)(bt >> 4) * SS * TT + (bt & 15)) * DD;

    // ---- LN lane assignment: 8 threads per row ----
    const int r_ln = tid >> 3;           // s-row 0..63 within chunk
    const int c8   = tid & 7;            // 16-float slot within the row
    const int slot_p = ((r_ln >> 2) & 3)*16 + (r_ln >> 4)*4 + (r_ln & 3);
    const int keyx   = slot_p & 7;
    const float* xp0 = x + base_bt + (size_t)r_ln * rowstride + c8*16;

    // ---- register prefetch of x chunk (16 VGPR) ----
    f32x4 px0, px1, px2, px3;
    auto issuePx = [&](int st) {
        const float* xp = xp0 + (size_t)st * CH * rowstride;
        px0 = *(const f32x4*)(xp + 0);
        px1 = *(const f32x4*)(xp + 4);
        px2 = *(const f32x4*)(xp + 8);
        px3 = *(const f32x4*)(xp + 12);
    };
    issuePx(0);   // latency hidden under the W-fragment build

    // ---- build W fragments + folded bias in-kernel ----
    short8 wfr[2][4];
    float  bs2[2];
    #pragma unroll
    for (int ni = 0; ni < 2; ++ni) {
        const int col = (ni ? 128 : 0) + w*16 + l15;
        float acc = 0.0f;
        #pragma unroll
        for (int kt = 0; kt < 4; ++kt) {
            union { short8 s8; uint32_t u[4]; } fr;
            #pragma unroll
            for (int p = 0; p < 4; ++p) {
                const int k0 = kt*32 + lhi*8 + 2*p;
                const float w0 = W[(size_t)k0*256 + col];
                const float w1 = W[(size_t)(k0+1)*256 + col];
                acc = fmaf(beta[k0],   w0, acc);
                acc = fmaf(beta[k0+1], w1, acc);
                fr.u[p] = cvt_pk_bf16(gamma[k0]*w0, gamma[k0+1]*w1);
            }
            wfr[ni][kt] = fr.s8;
        }
        acc += __shfl_xor(acc, 16);
        acc += __shfl_xor(acc, 32);
        bs2[ni] = bias[col] + acc;
    }

    // running h for this wave's 16 columns (replicated across lhi groups)
    float hM = prevh[(size_t)bt*128 + w*16 + l15];

    // ---- LN: consume px regs -> xnb[st&1] at permuted slot (swizzled) ----
    auto phaseLN = [&](int st) {
        float s1 = px0.x+px0.y+px0.z+px0.w + px1.x+px1.y+px1.z+px1.w
                 + px2.x+px2.y+px2.z+px2.w + px3.x+px3.y+px3.z+px3.w;
        float s2 = px0.x*px0.x+px0.y*px0.y+px0.z*px0.z+px0.w*px0.w
                 + px1.x*px1.x+px1.y*px1.y+px1.z*px1.z+px1.w*px1.w
                 + px2.x*px2.x+px2.y*px2.y+px2.z*px2.z+px2.w*px2.w
                 + px3.x*px3.x+px3.y*px3.y+px3.z*px3.z+px3.w*px3.w;
        s1 += __shfl_xor(s1, 1); s2 += __shfl_xor(s2, 1);
        s1 += __shfl_xor(s1, 2); s2 += __shfl_xor(s2, 2);
        s1 += __shfl_xor(s1, 4); s2 += __shfl_xor(s2, 4);
        const float mu = s1 * (1.0f/128.0f);
        const float rs = rsqrtf(s2 * (1.0f/128.0f) - mu*mu + LN_EPS);
        unsigned char* row = xnb[st & 1] + slot_p*256;
        union { short8 s8; uint32_t u[4]; } a, b2;
        a.u[0]  = cvt_pk_bf16((px0.x-mu)*rs, (px0.y-mu)*rs);
        a.u[1]  = cvt_pk_bf16((px0.z-mu)*rs, (px0.w-mu)*rs);
        a.u[2]  = cvt_pk_bf16((px1.x-mu)*rs, (px1.y-mu)*rs);
        a.u[3]  = cvt_pk_bf16((px1.z-mu)*rs, (px1.w-mu)*rs);
        b2.u[0] = cvt_pk_bf16((px2.x-mu)*rs, (px2.y-mu)*rs);
        b2.u[1] = cvt_pk_bf16((px2.z-mu)*rs, (px2.w-mu)*rs);
        b2.u[2] = cvt_pk_bf16((px3.x-mu)*rs, (px3.y-mu)*rs);
        b2.u[3] = cvt_pk_bf16((px3.z-mu)*rs, (px3.w-mu)*rs);
        *(short8*)(row + (((2*c8)     ^ keyx) << 4)) = a.s8;
        *(short8*)(row + (((2*c8 + 1) ^ keyx) << 4)) = b2.s8;
    };

    // ---- GEMM + activation + stage-wide in-register scan + out stores ----
    auto phaseG = [&](int st) {
        const unsigned char* xb = xnb[st & 1];
        float Cc[16], Cv[16];            // s = lhi*16 + idx, idx = mt*4 + j
        #pragma unroll
        for (int mt = 0; mt < 4; ++mt) {
            const unsigned char* rowp = xb + (mt*16 + l15)*256;
            short8 af[4];
            #pragma unroll
            for (int kt = 0; kt < 4; ++kt) {
                const int c = (kt << 2) | lhi;
                af[kt] = *(const short8*)(rowp + ((c ^ (l15 & 7)) << 4));
            }
            f32x4 ag = (f32x4)(0.f), ah = (f32x4)(0.f);
            #pragma unroll
            for (int kt = 0; kt < 4; ++kt) {
                ag = __builtin_amdgcn_mfma_f32_16x16x32_bf16(af[kt], wfr[0][kt], ag, 0, 0, 0);
                ah = __builtin_amdgcn_mfma_f32_16x16x32_bf16(af[kt], wfr[1][kt], ah, 0, 0, 0);
            }
            #pragma unroll
            for (int j = 0; j < 4; ++j) {
                const float g  = ag[j] + bs2[0];
                const float hh = ah[j] + bs2[1];
                const float cc = 1.0f / (1.0f + __expf(g));
                const float ga = (hh >= 0.0f) ? (hh + 0.5f)
                                              : (1.0f / (1.0f + __expf(-hh)));
                Cc[mt*4 + j] = cc;
                Cv[mt*4 + j] = (1.0f - cc) * ga;
            }
        }
        #pragma unroll
        for (int i = 1; i < 16; ++i) {       // lane-local prefix, 16 rows
            Cv[i] = fmaf(Cc[i], Cv[i-1], Cv[i]);
            Cc[i] = Cc[i] * Cc[i-1];
        }
        float Ic = Cc[15], Iv = Cv[15];      // cross-lhi Hillis-Steele
        float pc = __shfl_up(Ic, 16), pv = __shfl_up(Iv, 16);
        if (lhi >= 1) { Iv = fmaf(Ic, pv, Iv); Ic *= pc; }
        pc = __shfl_up(Ic, 32); pv = __shfl_up(Iv, 32);
        if (lhi >= 2) { Iv = fmaf(Ic, pv, Iv); Ic *= pc; }
        float Ec = __shfl_up(Ic, 16), Ev = __shfl_up(Iv, 16);
        if (lhi == 0) { Ec = 1.0f; Ev = 0.0f; }
        const float Mc = __shfl(Ic, 48 + l15);
        const float Mv = __shfl(Iv, 48 + l15);
        const float hE = fmaf(Ec, hM, Ev);   // h before row lhi*16
        float* op = out + base_bt + (size_t)(st*CH + lhi*16) * rowstride + w*16 + l15;
        #pragma unroll
        for (int i = 0; i < 16; ++i)
            op[(size_t)i * rowstride] = fmaf(Cc[i], hE, Cv[i]);
        hM = fmaf(Mc, hM, Mv);
    };

    // ---- prologue: LN(0) (waits px0), prefetch x(1) ----
    phaseLN(0);
    issuePx(1);
    BAR();

    // ---- main: one barrier per stage ----
    for (int st = 0; st < NCH; ++st) {
        phaseG(st);
        if (st + 1 < NCH) {
            phaseLN(st + 1);                 // consumes px(st+1)
            if (st + 2 < NCH) issuePx(st + 2);
        }
        BAR();
    }

    if (lane < 16)
        nexth[(size_t)bt*128 + w*16 + lane] = hM;
}

extern "C" void kernel_launch(void* const* d_in, const int* in_sizes, int n_in,
                              void* d_out, int out_size, void* d_ws, size_t ws_size,
                              hipStream_t stream) {
    const float* x     = (const float*)d_in[0];
    const float* prevh = (const float*)d_in[1];
    const float* gamma = (const float*)d_in[2];
    const float* beta  = (const float*)d_in[3];
    const float* W     = (const float*)d_in[4];
    const float* bias  = (const float*)d_in[5];

    float* out   = (float*)d_out;
    float* nexth = out + (size_t)BB*SS*TT*DD;              // 16777216

    fused_mingru<<<BB*TT, 512, 0, stream>>>(x, prevh, gamma, beta, W, bias,
                                            out, nexth);
}